// Round 5
// baseline (1546.280 us; speedup 1.0000x reference)
//
#include <hip/hip_runtime.h>

// RNNModule: LSTM-like scan with shared gate pre-activation.
// B=128, L=256, D=512, H=1024, O=2.
//
//  k0_prep : LDS-tiled transpose+convert Wh/Wx -> bf16 col-major (coalesced
//            both sides), bxh=bx+bh, zero flags, POISON hs (0xFFFF).
//  k1_xproj: xp[l][b][n] = bf16( x[b,l,:]@Wx[:,n] + bx[n] + bh[n] )
//  k2_scan : 256 steps, dataflow via per-wave flags. 8 groups (16 batch
//            rows) x 16 WGs (64 cols; wave owns 16 cols). R12 vs R8:
//            (1) group's 64 flags PACKED into 256B (2 lines) -> poll is a
//                coalesced 2-line L3 read, not a 64-line gather;
//            (2) producer skips the vmcnt(0) store-ack drain before the
//                flag store (-1 L3 RT/step). Flag may overtake data, so
//                the consumer validates the staged slice against the
//                0xFFFF sentinel (bf16 NaN -- unreachable: h=sg*tanh of
//                finite z is finite) and retries the rare race.
//            Poll cheap + stage once (R11 post-mortem: retry-refetch as
//            the poll primitive cost +166us; flags are the right poll).
//  k3_out  : out[b*L+l] = mask ? sigmoid(hs[l][b]@Wo + bo) : (0,1)

#define B_ 128
#define L_ 256
#define D_ 512
#define H_ 1024

// bar: 8 groups x 64 packed flags (4B each, 256B/group region)
#define GRP_FLAGS   64
#define BAR_ZERO    (8 * GRP_FLAGS)

typedef __attribute__((ext_vector_type(8))) short short8;
typedef __attribute__((ext_vector_type(4))) float f32x4;
typedef __attribute__((ext_vector_type(2))) float f32x2;
typedef __attribute__((ext_vector_type(4))) unsigned short u16x4;
typedef __attribute__((ext_vector_type(4))) int i32x4;

__device__ __forceinline__ unsigned short f2bf(float f) {
    unsigned int u = __float_as_uint(f);
    return (unsigned short)((u + 0x8000u) >> 16);  // round-half-up to bf16
}
__device__ __forceinline__ float bf2f(unsigned short s) {
    return __uint_as_float(((unsigned int)s) << 16);
}

// agent-scope 8B atomic store: write-through to the coherence point (L3)
__device__ __forceinline__ void st8(unsigned short* p, unsigned long long v) {
    __hip_atomic_store((unsigned long long*)p, v,
                       __ATOMIC_RELAXED, __HIP_MEMORY_SCOPE_AGENT);
}

// 16B load bypassing BOTH L1 (sc0) and the non-coherent XCD L2 (sc1):
// reads the coherence point (where producers' stores land).
template<int OFF>
__device__ __forceinline__ i32x4 ld16cc(const unsigned short* p) {
    i32x4 r;
    asm volatile("global_load_dwordx4 %0, %1, off offset:%2 sc0 sc1"
                 : "=v"(r) : "v"(p), "i"(OFF) : "memory");
    return r;
}

// drain with all 8 staged values tied: nothing can be scheduled earlier
__device__ __forceinline__ void wait_vm0_8(i32x4& a, i32x4& b, i32x4& c, i32x4& d,
                                           i32x4& e, i32x4& f, i32x4& g, i32x4& h) {
    asm volatile("s_waitcnt vmcnt(0)"
                 : "+v"(a), "+v"(b), "+v"(c), "+v"(d),
                   "+v"(e), "+v"(f), "+v"(g), "+v"(h) :: "memory");
}

// branchless: 1 if any u16 of the chunk is the 0xFFFF sentinel
__device__ __forceinline__ unsigned badchunk(i32x4 v) {
    unsigned bad = 0;
#pragma unroll
    for (int i = 0; i < 4; ++i) {
        unsigned d = (unsigned)v[i];
        bad |= ((d & 0xFFFFu) == 0xFFFFu);
        bad |= ((d >> 16)     == 0xFFFFu);
    }
    return bad;
}

// ---------------------------------------------------------------- k0: prep
// blk<256: Wh 64x64 tile transpose; blk<384: Wx tiles; blk 384: bxh+flags;
// blk>=385: poison hs with the 0xFFFF sentinel (re-done EVERY launch --
// stale values from a previous launch must not pass validation).
__global__ __launch_bounds__(256) void k0_prep(
    const float* __restrict__ Wh, const float* __restrict__ Wx,
    const float* __restrict__ bh, const float* __restrict__ bx,
    unsigned short* __restrict__ Whb_t, unsigned short* __restrict__ Wxb_t,
    float* __restrict__ bxh, int* __restrict__ bar,
    unsigned short* __restrict__ hs)
{
    __shared__ float tile[64][65];
    const int blk = blockIdx.x;
    const int t   = threadIdx.x;
    const int c   = t & 63, r0 = t >> 6;

    if (blk < 256) {            // Wh (1024x1024) -> Whb_t[n][k]
        const int tk = (blk >> 4) * 64, tn = (blk & 15) * 64;
#pragma unroll
        for (int i = 0; i < 16; ++i) {
            int r = i * 4 + r0;
            tile[r][c] = Wh[(size_t)(tk + r) * H_ + tn + c];
        }
        __syncthreads();
#pragma unroll
        for (int i = 0; i < 16; ++i) {
            int r = i * 4 + r0;
            Whb_t[(size_t)(tn + r) * H_ + tk + c] = f2bf(tile[c][r]);
        }
    } else if (blk < 384) {     // Wx (512x1024) -> Wxb_t[n][k]
        const int bi = blk - 256;
        const int tk = (bi >> 4) * 64, tn = (bi & 15) * 64;
#pragma unroll
        for (int i = 0; i < 16; ++i) {
            int r = i * 4 + r0;
            tile[r][c] = Wx[(size_t)(tk + r) * H_ + tn + c];
        }
        __syncthreads();
#pragma unroll
        for (int i = 0; i < 16; ++i) {
            int r = i * 4 + r0;
            Wxb_t[(size_t)(tn + r) * D_ + tk + c] = f2bf(tile[c][r]);
        }
    } else if (blk == 384) {
        for (int i = t; i < H_; i += 256) bxh[i] = bx[i] + bh[i];
        for (int i = t; i < BAR_ZERO; i += 256) bar[i] = 0;
    } else {
        // poison: 64 MiB = 4M 16B chunks; 2048 blks x 256 thr x 8 chunks
        const int pb = blk - 385;                    // 0..2047
        i32x4 s = { -1, -1, -1, -1 };                // 8x 0xFFFF
        i32x4* p = (i32x4*)hs;
        const size_t base = (size_t)pb * 256 + t;
#pragma unroll
        for (int i = 0; i < 8; ++i)
            p[base + (size_t)i * 524288] = s;
    }
}

// ------------------------------------------------------------ k1: x @ Wx
// Operand-swapped MFMA (A=Wx^T frag, B=x frag): D[row=outcol][col=batch],
// so each lane's 4 results are 4 consecutive n -> 8B store into xp[l][b][n].
__global__ __launch_bounds__(256) void k1_xproj(
    const float* __restrict__ x, const unsigned short* __restrict__ Wxb_t,
    const float* __restrict__ bxh, unsigned short* __restrict__ xp)
{
    const int nt   = blockIdx.x & 3;
    const int mt   = blockIdx.x >> 2;
    const int w    = threadIdx.x >> 6;
    const int lane = threadIdx.x & 63;
    const int m    = lane & 15, q = lane >> 4;
    const int m0   = mt * 64;
    const int l    = m0 >> 7;
    const int brow = (m0 & 127) + w * 16;
    const int n0   = nt * 256;

    const float* ap = x + ((size_t)(brow + m) * L_ + l) * D_ + q * 8;

    f32x4 acc[16];
#pragma unroll
    for (int t = 0; t < 16; ++t) acc[t] = (f32x4){0.f, 0.f, 0.f, 0.f};

#pragma unroll 4
    for (int kk = 0; kk < 16; ++kk) {
        f32x4 av0 = *(const f32x4*)(ap + kk * 32);
        f32x4 av1 = *(const f32x4*)(ap + kk * 32 + 4);
        short8 a8;
        a8[0] = (short)f2bf(av0[0]); a8[1] = (short)f2bf(av0[1]);
        a8[2] = (short)f2bf(av0[2]); a8[3] = (short)f2bf(av0[3]);
        a8[4] = (short)f2bf(av1[0]); a8[5] = (short)f2bf(av1[1]);
        a8[6] = (short)f2bf(av1[2]); a8[7] = (short)f2bf(av1[3]);
#pragma unroll
        for (int t = 0; t < 16; ++t) {
            short8 b8 = *(const short8*)(Wxb_t +
                        (size_t)(n0 + t * 16 + m) * D_ + kk * 32 + q * 8);
            acc[t] = __builtin_amdgcn_mfma_f32_16x16x32_bf16(b8, a8, acc[t], 0, 0, 0);
        }
    }

#pragma unroll
    for (int t = 0; t < 16; ++t) {
        const int c0 = n0 + t * 16 + q * 4;       // 4 consecutive out-cols
        f32x4 bias = *(const f32x4*)(bxh + c0);
        u16x4 o;
#pragma unroll
        for (int r = 0; r < 4; ++r) o[r] = f2bf(acc[t][r] + bias[r]);
        *(u16x4*)(xp + ((size_t)l * B_ + brow + m) * H_ + c0) = o;
    }
}

// ------------------------------------------------------------- k2: scan
// Grid: 128 WGs x 256 thr (4 waves, launch_bounds(256,1)). group g=blk&7
// (batch rows g*16..+15), wg=blk>>3 in [0,16) (cols wg*64..+63; wave owns 16).
// afrag pinned via opaque asm loads -> truly register-resident.
__global__ __launch_bounds__(256, 1) void k2_scan(
    const unsigned short* __restrict__ Whb_t,
    const unsigned short* __restrict__ xp,
    unsigned short* __restrict__ hs,
    int* __restrict__ bar)
{
    __shared__ unsigned short buf[2][16][1032];

    const int g    = blockIdx.x & 7;
    const int wg   = blockIdx.x >> 3;        // 0..15
    const int tid  = threadIdx.x;
    const int w    = tid >> 6;               // 0..3
    const int lane = tid & 63;
    const int mb   = lane & 15, q = lane >> 4;
    const int b0   = g * 16;
    const int colw = wg * 64 + w * 16;       // wave's 16-col tile

    // persistent A fragments: Wh^T[colw+mb][k], k = kk*32 + q*8 + j.
    // Loaded via OPAQUE asm (cannot be rematerialized/sunk into the loop),
    // anchored after the drain -> 128 VGPRs live for the whole scan.
    short8 afrag[32];
    {
        const unsigned short* wp = Whb_t + (size_t)(colw + mb) * H_ + q * 8;
#pragma unroll
        for (int kk = 0; kk < 32; ++kk)
            asm volatile("global_load_dwordx4 %0, %1, off offset:%2"
                         : "=v"(afrag[kk]) : "v"(wp), "i"(kk * 64));
        asm volatile("s_waitcnt vmcnt(0)" ::: "memory");
#pragma unroll
        for (int kk = 0; kk < 32; ++kk)
            asm volatile("" : "+v"(afrag[kk]));
    }

    int* flags  = bar + g * GRP_FLAGS;        // 64 packed flags (2 lines)
    int* myflag = flags + (wg * 4 + w);

    // staging mapping: thread -> row srow, 16B-chunks sci + 16i (i<8)
    const int srow = tid >> 4;   // 0..15
    const int sci  = tid & 15;   // 0..15

    float c[4] = {0.f, 0.f, 0.f, 0.f};

    for (int l = 0; l < L_; ++l) {
        // xp addend (independent of recurrence): issue early
        u16x4 xv = *(const u16x4*)(xp + ((size_t)l * B_ + b0 + mb) * H_ + colw + q * 4);

        unsigned short* lbuf = &buf[l & 1][0][0];
        if (l > 0) {
            // wait: all 64 producer waves of this group published h(l-1).
            // lane i polls flag i -- PACKED: one coalesced 2-line read.
            while (true) {
                int f = __hip_atomic_load(flags + lane,
                         __ATOMIC_RELAXED, __HIP_MEMORY_SCOPE_AGENT);
                if (__all(f >= l)) break;
            }
            // stage h[l-1] slice (16x1024, 32 KB) -> validate -> LDS.
            // Flag may have overtaken data (producer skips the ack drain),
            // so reject sentinel chunks and re-load (rare, ~store-flight).
            const unsigned short* gp =
                hs + ((size_t)(l - 1) * B_ + b0 + srow) * H_ + sci * 8;
            i32x4 v0, v1, v2, v3, v4, v5, v6, v7;
            while (true) {
                v0 = ld16cc<0>(gp);    v1 = ld16cc<256>(gp);
                v2 = ld16cc<512>(gp);  v3 = ld16cc<768>(gp);
                v4 = ld16cc<1024>(gp); v5 = ld16cc<1280>(gp);
                v6 = ld16cc<1536>(gp); v7 = ld16cc<1792>(gp);
                wait_vm0_8(v0, v1, v2, v3, v4, v5, v6, v7);
                unsigned bad = badchunk(v0) | badchunk(v1) | badchunk(v2) |
                               badchunk(v3) | badchunk(v4) | badchunk(v5) |
                               badchunk(v6) | badchunk(v7);
                if (!bad) break;
            }
            unsigned short* lp = lbuf + srow * 1032 + sci * 8;
            *(i32x4*)(lp)        = v0;  *(i32x4*)(lp + 128)  = v1;
            *(i32x4*)(lp + 256)  = v2;  *(i32x4*)(lp + 384)  = v3;
            *(i32x4*)(lp + 512)  = v4;  *(i32x4*)(lp + 640)  = v5;
            *(i32x4*)(lp + 768)  = v6;  *(i32x4*)(lp + 896)  = v7;
        }
        __syncthreads();   // staging visible to all waves; dbuf protects l+1

        f32x4 acc0 = {0.f,0.f,0.f,0.f}, acc1 = {0.f,0.f,0.f,0.f};
        f32x4 acc2 = {0.f,0.f,0.f,0.f}, acc3 = {0.f,0.f,0.f,0.f};
        if (l > 0) {
            // B fragments from LDS: lane (mb,q) reads h[mb][kb*32+q*8 ..+7]
            const unsigned short* rp = lbuf + mb * 1032 + q * 8;
#pragma unroll
            for (int kb = 0; kb < 32; kb += 4) {
                short8 bb0 = *(const short8*)(rp + (kb + 0) * 32);
                short8 bb1 = *(const short8*)(rp + (kb + 1) * 32);
                short8 bb2 = *(const short8*)(rp + (kb + 2) * 32);
                short8 bb3 = *(const short8*)(rp + (kb + 3) * 32);
                acc0 = __builtin_amdgcn_mfma_f32_16x16x32_bf16(afrag[kb + 0], bb0, acc0, 0, 0, 0);
                acc1 = __builtin_amdgcn_mfma_f32_16x16x32_bf16(afrag[kb + 1], bb1, acc1, 0, 0, 0);
                acc2 = __builtin_amdgcn_mfma_f32_16x16x32_bf16(afrag[kb + 2], bb2, acc2, 0, 0, 0);
                acc3 = __builtin_amdgcn_mfma_f32_16x16x32_bf16(afrag[kb + 3], bb3, acc3, 0, 0, 0);
            }
        }
        // gate math: lane (mb,q) -> batch b0+mb, cols colw+q*4+r
        u16x4 o;
#pragma unroll
        for (int r = 0; r < 4; ++r) {
            float z  = acc0[r] + acc1[r] + acc2[r] + acc3[r] + bf2f(xv[r]);
            float e  = __expf(-z);
            float sg = 1.f / (1.f + e);           // sigmoid(z)
            float gg = 2.f / (1.f + e * e) - 1.f; // tanh(z) via same exp
            c[r] = sg * (c[r] + gg);
            float ec = __expf(-2.f * c[r]);
            float th = 2.f / (1.f + ec) - 1.f;    // tanh(c)
            o[r] = f2bf(sg * th);
        }
        union { u16x4 v; unsigned long long u; } hu;
        hu.v = o;
        // store h then flag WITHOUT ack drain: consumers validate data.
        st8(hs + ((size_t)l * B_ + b0 + mb) * H_ + colw + q * 4, hu.u);
        if (lane == 0)
            __hip_atomic_store(myflag, l + 1,
                               __ATOMIC_RELAXED, __HIP_MEMORY_SCOPE_AGENT);
    }
}

// ------------------------------------------------------------- k3: output
// Kernel-dispatch boundaries perform the HSA acquire (cache invalidate), so
// plain loads of hs are safe here.
__global__ __launch_bounds__(256) void k3_out(
    const unsigned short* __restrict__ hs,
    const float* __restrict__ Wo, const float* __restrict__ bo,
    const int* __restrict__ slen, float* __restrict__ out)
{
    const int w    = threadIdx.x >> 6;
    const int lane = threadIdx.x & 63;
    const int r    = blockIdx.x * 4 + w;   // r = b*L + l
    const int b    = r >> 8;
    const int l    = r & 255;

    const unsigned short* hp = hs + ((size_t)l * B_ + b) * H_ + lane * 16;
    const float* wp = Wo + (size_t)lane * 32;
    float u0 = 0.f, u1 = 0.f;
#pragma unroll
    for (int j0 = 0; j0 < 16; j0 += 8) {
        short8 hv = *(const short8*)(hp + j0);
#pragma unroll
        for (int j = 0; j < 8; ++j) {
            float h = bf2f((unsigned short)hv[j]);
            f32x2 wv = *(const f32x2*)(wp + (j0 + j) * 2);
            u0 += h * wv[0];
            u1 += h * wv[1];
        }
    }
#pragma unroll
    for (int off = 32; off; off >>= 1) {
        u0 += __shfl_down(u0, off);
        u1 += __shfl_down(u1, off);
    }
    if (lane == 0) {
        float o0, o1;
        if (l <= slen[b]) {
            o0 = 1.f / (1.f + __expf(-(u0 + bo[0])));
            o1 = 1.f / (1.f + __expf(-(u1 + bo[1])));
        } else {
            o0 = 0.f; o1 = 1.f;
        }
        out[(size_t)r * 2]     = o0;
        out[(size_t)r * 2 + 1] = o1;
    }
}

// ----------------------------------------------------------------- launch
extern "C" void kernel_launch(void* const* d_in, const int* in_sizes, int n_in,
                              void* d_out, int out_size, void* d_ws, size_t ws_size,
                              hipStream_t stream)
{
    const float* x    = (const float*)d_in[0];
    const int*   slen = (const int*)d_in[1];
    const float* Wh   = (const float*)d_in[2];
    const float* bh   = (const float*)d_in[3];
    const float* Wx   = (const float*)d_in[4];
    const float* bx   = (const float*)d_in[5];
    const float* Wo   = (const float*)d_in[6];
    const float* bo   = (const float*)d_in[7];
    float* out = (float*)d_out;

    char* ws = (char*)d_ws;
    unsigned short* Whb_t = (unsigned short*)(ws);                     // 2 MiB
    unsigned short* Wxb_t = (unsigned short*)(ws + (2u << 20));        // 1 MiB
    float*          bxh   = (float*)(ws + (3u << 20));                 // 4 KiB
    int*            bar   = (int*)(ws + (3u << 20) + 65536);           // 8 KiB
    unsigned short* xp    = (unsigned short*)(ws + (4u << 20));        // 64 MiB
    unsigned short* hs    = (unsigned short*)(ws + (68u << 20));       // 64 MiB

    k0_prep<<<2433, 256, 0, stream>>>(Wh, Wx, bh, bx, Whb_t, Wxb_t, bxh, bar, hs);
    k1_xproj<<<2048, 256, 0, stream>>>(x, Wxb_t, bxh, xp);
    k2_scan<<<128, 256, 0, stream>>>(Whb_t, xp, hs, bar);
    k3_out<<<8192, 256, 0, stream>>>(hs, Wo, bo, slen, out);
}

// Round 7
// 1371.186 us; speedup vs baseline: 1.1277x; 1.1277x over previous
//
#include <hip/hip_runtime.h>

// RNNModule: LSTM-like scan with shared gate pre-activation.
// B=128, L=256, D=512, H=1024, O=2.
//
//  k0_prep : LDS-tiled transpose+convert Wh/Wx -> bf16 col-major (coalesced
//            both sides), bxh=bx+bh, zero flags.
//  k1_xproj: xp[l][b][n] = bf16( x[b,l,:]@Wx[:,n] + bx[n] + bh[n] )
//  k2_scan : 256 steps, R8 flag protocol verbatim (spread 64B-stride flags,
//            producer store->drain->flag, poll-then-stage). R14 structure:
//            64 WGs x 512 thr (8 waves) -- R13's 1024-thr version could not
//            launch (afrag pins 128 VGPRs; 16 waves/CU needs <=128 total).
//            8 WGs/group of 8 waves; wave owns 16 cols (unchanged body).
//            Levers vs R8: staging traffic /2 (8 WGs re-read the 32KB
//            slice, not 16; 4 chunks/thread), poll traffic /8 (only wave0
//            of each WG polls, +1 barrier to release siblings). R11/R12
//            taught: packed flags and data-as-flag LOSE; the excess over
//            naive latency is CONTENTION -> cut contending agents.
//  k3_out  : out[b*L+l] = mask ? sigmoid(hs[l][b]@Wo + bo) : (0,1)

#define B_ 128
#define L_ 256
#define D_ 512
#define H_ 1024

typedef __attribute__((ext_vector_type(8))) short short8;
typedef __attribute__((ext_vector_type(4))) float f32x4;
typedef __attribute__((ext_vector_type(2))) float f32x2;
typedef __attribute__((ext_vector_type(4))) unsigned short u16x4;
typedef __attribute__((ext_vector_type(4))) int i32x4;

__device__ __forceinline__ unsigned short f2bf(float f) {
    unsigned int u = __float_as_uint(f);
    return (unsigned short)((u + 0x8000u) >> 16);  // round-half-up to bf16
}
__device__ __forceinline__ float bf2f(unsigned short s) {
    return __uint_as_float(((unsigned int)s) << 16);
}

// agent-scope 8B atomic store: write-through to the coherence point (L3)
__device__ __forceinline__ void st8(unsigned short* p, unsigned long long v) {
    __hip_atomic_store((unsigned long long*)p, v,
                       __ATOMIC_RELAXED, __HIP_MEMORY_SCOPE_AGENT);
}

// 16B load bypassing BOTH L1 (sc0) and the non-coherent XCD L2 (sc1):
// reads the coherence point (where producers' stores land).
template<int OFF>
__device__ __forceinline__ i32x4 ld16cc(const unsigned short* p) {
    i32x4 r;
    asm volatile("global_load_dwordx4 %0, %1, off offset:%2 sc0 sc1"
                 : "=v"(r) : "v"(p), "i"(OFF) : "memory");
    return r;
}

// staged drains: pin tied values so no use is scheduled earlier
__device__ __forceinline__ void wait_vm2(i32x4& a, i32x4& b) {
    asm volatile("s_waitcnt vmcnt(2)" : "+v"(a), "+v"(b) :: "memory");
}
__device__ __forceinline__ void wait_vm0_2(i32x4& a, i32x4& b) {
    asm volatile("s_waitcnt vmcnt(0)" : "+v"(a), "+v"(b) :: "memory");
}
// release-drain: own data stores ack'd at the coherence point
__device__ __forceinline__ void release_vm0() {
    asm volatile("s_waitcnt vmcnt(0)" ::: "memory");
}

// ---------------------------------------------------------------- k0: prep
// blk<256: Wh 64x64 tile transpose; blk<384: Wx tiles; blk 384: bxh+flags.
__global__ __launch_bounds__(256) void k0_prep(
    const float* __restrict__ Wh, const float* __restrict__ Wx,
    const float* __restrict__ bh, const float* __restrict__ bx,
    unsigned short* __restrict__ Whb_t, unsigned short* __restrict__ Wxb_t,
    float* __restrict__ bxh, int* __restrict__ bar)
{
    __shared__ float tile[64][65];
    const int blk = blockIdx.x;
    const int t   = threadIdx.x;
    const int c   = t & 63, r0 = t >> 6;

    if (blk < 256) {            // Wh (1024x1024) -> Whb_t[n][k]
        const int tk = (blk >> 4) * 64, tn = (blk & 15) * 64;
#pragma unroll
        for (int i = 0; i < 16; ++i) {
            int r = i * 4 + r0;
            tile[r][c] = Wh[(size_t)(tk + r) * H_ + tn + c];
        }
        __syncthreads();
#pragma unroll
        for (int i = 0; i < 16; ++i) {
            int r = i * 4 + r0;
            Whb_t[(size_t)(tn + r) * H_ + tk + c] = f2bf(tile[c][r]);
        }
    } else if (blk < 384) {     // Wx (512x1024) -> Wxb_t[n][k]
        const int bi = blk - 256;
        const int tk = (bi >> 4) * 64, tn = (bi & 15) * 64;
#pragma unroll
        for (int i = 0; i < 16; ++i) {
            int r = i * 4 + r0;
            tile[r][c] = Wx[(size_t)(tk + r) * H_ + tn + c];
        }
        __syncthreads();
#pragma unroll
        for (int i = 0; i < 16; ++i) {
            int r = i * 4 + r0;
            Wxb_t[(size_t)(tn + r) * D_ + tk + c] = f2bf(tile[c][r]);
        }
    } else {
        for (int i = t; i < H_; i += 256) bxh[i] = bx[i] + bh[i];
        for (int i = t; i < 8 * 1024; i += 256) bar[i] = 0;
    }
}

// ------------------------------------------------------------ k1: x @ Wx
// Operand-swapped MFMA (A=Wx^T frag, B=x frag): D[row=outcol][col=batch],
// so each lane's 4 results are 4 consecutive n -> 8B store into xp[l][b][n].
__global__ __launch_bounds__(256) void k1_xproj(
    const float* __restrict__ x, const unsigned short* __restrict__ Wxb_t,
    const float* __restrict__ bxh, unsigned short* __restrict__ xp)
{
    const int nt   = blockIdx.x & 3;
    const int mt   = blockIdx.x >> 2;
    const int w    = threadIdx.x >> 6;
    const int lane = threadIdx.x & 63;
    const int m    = lane & 15, q = lane >> 4;
    const int m0   = mt * 64;
    const int l    = m0 >> 7;
    const int brow = (m0 & 127) + w * 16;
    const int n0   = nt * 256;

    const float* ap = x + ((size_t)(brow + m) * L_ + l) * D_ + q * 8;

    f32x4 acc[16];
#pragma unroll
    for (int t = 0; t < 16; ++t) acc[t] = (f32x4){0.f, 0.f, 0.f, 0.f};

#pragma unroll 4
    for (int kk = 0; kk < 16; ++kk) {
        f32x4 av0 = *(const f32x4*)(ap + kk * 32);
        f32x4 av1 = *(const f32x4*)(ap + kk * 32 + 4);
        short8 a8;
        a8[0] = (short)f2bf(av0[0]); a8[1] = (short)f2bf(av0[1]);
        a8[2] = (short)f2bf(av0[2]); a8[3] = (short)f2bf(av0[3]);
        a8[4] = (short)f2bf(av1[0]); a8[5] = (short)f2bf(av1[1]);
        a8[6] = (short)f2bf(av1[2]); a8[7] = (short)f2bf(av1[3]);
#pragma unroll
        for (int t = 0; t < 16; ++t) {
            short8 b8 = *(const short8*)(Wxb_t +
                        (size_t)(n0 + t * 16 + m) * D_ + kk * 32 + q * 8);
            acc[t] = __builtin_amdgcn_mfma_f32_16x16x32_bf16(b8, a8, acc[t], 0, 0, 0);
        }
    }

#pragma unroll
    for (int t = 0; t < 16; ++t) {
        const int c0 = n0 + t * 16 + q * 4;       // 4 consecutive out-cols
        f32x4 bias = *(const f32x4*)(bxh + c0);
        u16x4 o;
#pragma unroll
        for (int r = 0; r < 4; ++r) o[r] = f2bf(acc[t][r] + bias[r]);
        *(u16x4*)(xp + ((size_t)l * B_ + brow + m) * H_ + c0) = o;
    }
}

// ------------------------------------------------------------- k2: scan
// Grid: 64 WGs x 512 thr (8 waves, launch_bounds(512,1)). group g=blk&7
// (batch rows g*16..+15), wgi=blk>>3 in [0,8) (cols wgi*128..+127; wave
// owns 16 cols). Per-wave spread flags (64B stride) exactly as R8.
// Only wave 0 of each WG polls; a barrier releases the other 7 waves.
__global__ __launch_bounds__(512, 1) void k2_scan(
    const unsigned short* __restrict__ Whb_t,
    const unsigned short* __restrict__ xp,
    unsigned short* __restrict__ hs,
    int* __restrict__ bar)
{
    __shared__ unsigned short buf[2][16][1032];

    const int g    = blockIdx.x & 7;
    const int wgi  = blockIdx.x >> 3;        // 0..7
    const int tid  = threadIdx.x;
    const int w    = tid >> 6;               // 0..7
    const int lane = tid & 63;
    const int mb   = lane & 15, q = lane >> 4;
    const int b0   = g * 16;
    const int colw = wgi * 128 + w * 16;     // wave's 16-col tile

    // persistent A fragments: Wh^T[colw+mb][k], k = kk*32 + q*8 + j.
    // Loaded via OPAQUE asm (cannot be rematerialized/sunk into the loop),
    // anchored after the drain -> 128 VGPRs live for the whole scan.
    short8 afrag[32];
    {
        const unsigned short* wp = Whb_t + (size_t)(colw + mb) * H_ + q * 8;
#pragma unroll
        for (int kk = 0; kk < 32; ++kk)
            asm volatile("global_load_dwordx4 %0, %1, off offset:%2"
                         : "=v"(afrag[kk]) : "v"(wp), "i"(kk * 64));
        asm volatile("s_waitcnt vmcnt(0)" ::: "memory");
#pragma unroll
        for (int kk = 0; kk < 32; ++kk)
            asm volatile("" : "+v"(afrag[kk]));
    }

    int* flags  = bar + g * 1024;                   // 64 wave-flags, stride 16
    int* myflag = flags + (wgi * 8 + w) * 16;

    // staging mapping: thread -> row srow (tid>>5), 16B-chunks sci + 32i (i<4)
    const int srow = tid >> 5;   // 0..15
    const int sci  = tid & 31;   // 0..31

    float c[4] = {0.f, 0.f, 0.f, 0.f};

    for (int l = 0; l < L_; ++l) {
        // xp addend (independent of recurrence): issue early
        u16x4 xv = *(const u16x4*)(xp + ((size_t)l * B_ + b0 + mb) * H_ + colw + q * 4);

        unsigned short* lbuf = &buf[l & 1][0][0];
        if (l > 0) {
            // wait: all 64 producer waves of this group published h(l-1).
            // ONLY wave 0 polls (lane i -> flag i); barrier releases rest.
            if (w == 0) {
                while (true) {
                    int f = __hip_atomic_load(flags + lane * 16,
                             __ATOMIC_RELAXED, __HIP_MEMORY_SCOPE_AGENT);
                    if (__all(f >= l)) break;
                }
            }
            __syncthreads();
            // ONE staging pass: h[l-1] slice (16x1024, 32 KB) -> LDS.
            // 512 threads x 4 chunks; split drain overlaps write/flight.
            const unsigned short* gp =
                hs + ((size_t)(l - 1) * B_ + b0 + srow) * H_ + sci * 8;
            i32x4 v0, v1, v2, v3;
            v0 = ld16cc<0>(gp);    v1 = ld16cc<512>(gp);
            v2 = ld16cc<1024>(gp); v3 = ld16cc<1536>(gp);
            unsigned short* lp = lbuf + srow * 1032 + sci * 8;
            wait_vm2(v0, v1);
            *(i32x4*)(lp)        = v0;  *(i32x4*)(lp + 256)  = v1;
            wait_vm0_2(v2, v3);
            *(i32x4*)(lp + 512)  = v2;  *(i32x4*)(lp + 768)  = v3;
        }
        __syncthreads();   // staging visible to all waves; dbuf protects l+1

        f32x4 acc0 = {0.f,0.f,0.f,0.f}, acc1 = {0.f,0.f,0.f,0.f};
        f32x4 acc2 = {0.f,0.f,0.f,0.f}, acc3 = {0.f,0.f,0.f,0.f};
        if (l > 0) {
            // B fragments from LDS: lane (mb,q) reads h[mb][kb*32+q*8 ..+7]
            const unsigned short* rp = lbuf + mb * 1032 + q * 8;
#pragma unroll
            for (int kb = 0; kb < 32; kb += 4) {
                short8 bb0 = *(const short8*)(rp + (kb + 0) * 32);
                short8 bb1 = *(const short8*)(rp + (kb + 1) * 32);
                short8 bb2 = *(const short8*)(rp + (kb + 2) * 32);
                short8 bb3 = *(const short8*)(rp + (kb + 3) * 32);
                acc0 = __builtin_amdgcn_mfma_f32_16x16x32_bf16(afrag[kb + 0], bb0, acc0, 0, 0, 0);
                acc1 = __builtin_amdgcn_mfma_f32_16x16x32_bf16(afrag[kb + 1], bb1, acc1, 0, 0, 0);
                acc2 = __builtin_amdgcn_mfma_f32_16x16x32_bf16(afrag[kb + 2], bb2, acc2, 0, 0, 0);
                acc3 = __builtin_amdgcn_mfma_f32_16x16x32_bf16(afrag[kb + 3], bb3, acc3, 0, 0, 0);
            }
        }
        // gate math: lane (mb,q) -> batch b0+mb, cols colw+q*4+r
        u16x4 o;
#pragma unroll
        for (int r = 0; r < 4; ++r) {
            float z  = acc0[r] + acc1[r] + acc2[r] + acc3[r] + bf2f(xv[r]);
            float e  = __expf(-z);
            float sg = 1.f / (1.f + e);           // sigmoid(z)
            float gg = 2.f / (1.f + e * e) - 1.f; // tanh(z) via same exp
            c[r] = sg * (c[r] + gg);
            float ec = __expf(-2.f * c[r]);
            float th = 2.f / (1.f + ec) - 1.f;    // tanh(c)
            o[r] = f2bf(sg * th);
        }
        union { u16x4 v; unsigned long long u; } hu;
        hu.v = o;
        st8(hs + ((size_t)l * B_ + b0 + mb) * H_ + colw + q * 4, hu.u);
        // per-wave release: own stores ack'd at coherence point, then flag
        release_vm0();
        if (lane == 0)
            __hip_atomic_store(myflag, l + 1,
                               __ATOMIC_RELAXED, __HIP_MEMORY_SCOPE_AGENT);
    }
}

// ------------------------------------------------------------- k3: output
// Kernel-dispatch boundaries perform the HSA acquire (cache invalidate), so
// plain loads of hs are safe here.
__global__ __launch_bounds__(256) void k3_out(
    const unsigned short* __restrict__ hs,
    const float* __restrict__ Wo, const float* __restrict__ bo,
    const int* __restrict__ slen, float* __restrict__ out)
{
    const int w    = threadIdx.x >> 6;
    const int lane = threadIdx.x & 63;
    const int r    = blockIdx.x * 4 + w;   // r = b*L + l
    const int b    = r >> 8;
    const int l    = r & 255;

    const unsigned short* hp = hs + ((size_t)l * B_ + b) * H_ + lane * 16;
    const float* wp = Wo + (size_t)lane * 32;
    float u0 = 0.f, u1 = 0.f;
#pragma unroll
    for (int j0 = 0; j0 < 16; j0 += 8) {
        short8 hv = *(const short8*)(hp + j0);
#pragma unroll
        for (int j = 0; j < 8; ++j) {
            float h = bf2f((unsigned short)hv[j]);
            f32x2 wv = *(const f32x2*)(wp + (j0 + j) * 2);
            u0 += h * wv[0];
            u1 += h * wv[1];
        }
    }
#pragma unroll
    for (int off = 32; off; off >>= 1) {
        u0 += __shfl_down(u0, off);
        u1 += __shfl_down(u1, off);
    }
    if (lane == 0) {
        float o0, o1;
        if (l <= slen[b]) {
            o0 = 1.f / (1.f + __expf(-(u0 + bo[0])));
            o1 = 1.f / (1.f + __expf(-(u1 + bo[1])));
        } else {
            o0 = 0.f; o1 = 1.f;
        }
        out[(size_t)r * 2]     = o0;
        out[(size_t)r * 2 + 1] = o1;
    }
}

// ----------------------------------------------------------------- launch
extern "C" void kernel_launch(void* const* d_in, const int* in_sizes, int n_in,
                              void* d_out, int out_size, void* d_ws, size_t ws_size,
                              hipStream_t stream)
{
    const float* x    = (const float*)d_in[0];
    const int*   slen = (const int*)d_in[1];
    const float* Wh   = (const float*)d_in[2];
    const float* bh   = (const float*)d_in[3];
    const float* Wx   = (const float*)d_in[4];
    const float* bx   = (const float*)d_in[5];
    const float* Wo   = (const float*)d_in[6];
    const float* bo   = (const float*)d_in[7];
    float* out = (float*)d_out;

    char* ws = (char*)d_ws;
    unsigned short* Whb_t = (unsigned short*)(ws);                     // 2 MiB
    unsigned short* Wxb_t = (unsigned short*)(ws + (2u << 20));        // 1 MiB
    float*          bxh   = (float*)(ws + (3u << 20));                 // 4 KiB
    int*            bar   = (int*)(ws + (3u << 20) + 65536);           // 32 KiB
    unsigned short* xp    = (unsigned short*)(ws + (4u << 20));        // 64 MiB
    unsigned short* hs    = (unsigned short*)(ws + (68u << 20));       // 64 MiB

    k0_prep<<<385, 256, 0, stream>>>(Wh, Wx, bh, bx, Whb_t, Wxb_t, bxh, bar);
    k1_xproj<<<2048, 256, 0, stream>>>(x, Wxb_t, bxh, xp);
    k2_scan<<<64, 512, 0, stream>>>(Whb_t, xp, hs, bar);
    k3_out<<<8192, 256, 0, stream>>>(hs, Wo, bo, slen, out);
}